// Round 13
// baseline (142.735 us; speedup 1.0000x reference)
//
#include <hip/hip_runtime.h>
#include <math.h>

#define NUM_ITER 10
#define Z_MIN 0.1f

typedef float v2f __attribute__((ext_vector_type(2)));

__device__ inline float uniform_f(float v) {
    return __int_as_float(__builtin_amdgcn_readfirstlane(__float_as_int(v)));
}

__device__ inline float fast_rcp(float x) {
    return __builtin_amdgcn_rcpf(x);
}

__device__ inline v2f fma2(v2f a, v2f b, v2f c) {
#if __has_builtin(__builtin_elementwise_fma)
    return __builtin_elementwise_fma(a, b, c);   // -> v_pk_fma_f32
#else
    v2f r; r.x = fmaf(a.x, b.x, c.x); r.y = fmaf(a.y, b.y, c.y); return r;
#endif
}

__device__ inline v2f max2(v2f a, v2f b) {
#if __has_builtin(__builtin_elementwise_max)
    return __builtin_elementwise_max(a, b);
#else
    v2f r; r.x = fmaxf(a.x, b.x); r.y = fmaxf(a.y, b.y); return r;
#endif
}

// Full-wave (64-lane) reduce, ALL-VALU: 4x DPP row_ror + row_bcast15 +
// row_bcast31 -> total in lanes 48-63; v_readlane(63) -> uniform SGPR.
template <int M>
__device__ inline void wave_reduce_uniform(float (&a)[M]) {
#pragma unroll
    for (int k = 0; k < M; ++k) {
        int t = __builtin_amdgcn_update_dpp(0, __float_as_int(a[k]), 0x121, 0xf, 0xf, true);
        a[k] += __int_as_float(t);  // ror:1
    }
#pragma unroll
    for (int k = 0; k < M; ++k) {
        int t = __builtin_amdgcn_update_dpp(0, __float_as_int(a[k]), 0x122, 0xf, 0xf, true);
        a[k] += __int_as_float(t);  // ror:2
    }
#pragma unroll
    for (int k = 0; k < M; ++k) {
        int t = __builtin_amdgcn_update_dpp(0, __float_as_int(a[k]), 0x124, 0xf, 0xf, true);
        a[k] += __int_as_float(t);  // ror:4
    }
#pragma unroll
    for (int k = 0; k < M; ++k) {
        int t = __builtin_amdgcn_update_dpp(0, __float_as_int(a[k]), 0x128, 0xf, 0xf, true);
        a[k] += __int_as_float(t);  // ror:8
    }
#pragma unroll
    for (int k = 0; k < M; ++k) {
        int t = __builtin_amdgcn_update_dpp(0, __float_as_int(a[k]), 0x142, 0xf, 0xf, true);
        a[k] += __int_as_float(t);  // row_bcast15
    }
#pragma unroll
    for (int k = 0; k < M; ++k) {
        int t = __builtin_amdgcn_update_dpp(0, __float_as_int(a[k]), 0x143, 0xf, 0xf, true);
        a[k] += __int_as_float(t);  // row_bcast31
    }
#pragma unroll
    for (int k = 0; k < M; ++k) {
        a[k] = __int_as_float(__builtin_amdgcn_readlane(__float_as_int(a[k]), 63));
    }
}

// Branchless f32 LDL^T solve of 4x4 SPD system. t = upper-tri packed
// (00,01,02,03,11,12,13,22,23,33), solves A x = b.
__device__ inline void solve4_spd(const float t[10], const float b[4], float x[4]) {
    const float d0 = t[0];
    const float i0 = fast_rcp(d0);
    const float L10 = t[1] * i0, L20 = t[2] * i0, L30 = t[3] * i0;
    const float d1 = t[4] - L10 * t[1];
    const float i1 = fast_rcp(d1);
    const float L21 = (t[5] - L20 * t[1]) * i1;
    const float L31 = (t[6] - L30 * t[1]) * i1;
    const float d2 = t[7] - L20 * t[2] - L21 * L21 * d1;
    const float i2 = fast_rcp(d2);
    const float L32 = (t[8] - L30 * t[2] - L31 * L21 * d1) * i2;
    const float d3 = t[9] - L30 * t[3] - L31 * L31 * d1 - L32 * L32 * d2;
    const float i3 = fast_rcp(d3);
    const float y0 = b[0];
    const float y1 = b[1] - L10 * y0;
    const float y2 = b[2] - L20 * y0 - L21 * y1;
    const float y3 = b[3] - L30 * y0 - L31 * y1 - L32 * y2;
    const float z0 = y0 * i0, z1 = y1 * i1, z2 = y2 * i2, z3 = y3 * i3;
    x[3] = z3;
    x[2] = z2 - L32 * z3;
    x[1] = z1 - L21 * x[2] - L31 * x[3];
    x[0] = z0 - L10 * x[1] - L20 * x[2] - L30 * x[3];
}

// TWO waves per batch item (8192 waves -> ~8/SIMD, was 4). Block = 256 =
// 4 waves = 2 items. Each wave owns half the points (NP pairs/lane,
// packed-f32 math); per-iteration partials combined across halves via a
// double-buffered LDS slot + one __syncthreads; both halves then run
// bitwise-identical control. Rationale: R8-R11 showed latency-bound with
// ~40% idle issue slots at grid-capped 4 waves/SIMD; doubling TLP fills
// those slots, duplicated reduce/control lands in otherwise-dead cycles.
// R13 FIX vs R12: EXACT half-offsets were 2x too large (3*NP*64 / 2*NP*64
// float4) -> OOB reads on last item -> memory fault. Correct strides:
// half wh owns 128*NP points = wh*(3*NP*32) float4 of x3d and
// wh*(2*NP*32) float4 of x2d/w2d.
template <int NP, bool EXACT>
__global__ __launch_bounds__(256) void lm_kernel2(
    const float* __restrict__ x3d, const float* __restrict__ x2d,
    const float* __restrict__ w2d, const float* __restrict__ pose_init,
    const float* __restrict__ K, float* __restrict__ out, int B, int N)
{
    const int wave = threadIdx.x >> 6;   // 0..3
    const int lane = threadIdx.x & 63;
    const int ib   = wave >> 1;          // item within block: 0..1
    const int wh   = wave & 1;           // half within item: 0..1
    int item = blockIdx.x * 2 + ib;
    const bool valid = (item < B);
    if (!valid) item = B - 1;            // clamp; all waves must reach barriers

    // [item-in-block][iteration parity][half][sum]  (<=15 sums used)
    __shared__ float red[2][2][2][15];

    // ---- K: loop-invariant, wave-uniform -> SGPRs ----
    const float* Kb = K + (size_t)item * 9;
    const float K00 = uniform_f(Kb[0]), K01 = uniform_f(Kb[1]), K02 = uniform_f(Kb[2]);
    const float K10 = uniform_f(Kb[3]), K11 = uniform_f(Kb[4]), K12 = uniform_f(Kb[5]);
    const float K20 = uniform_f(Kb[6]), K21 = uniform_f(Kb[7]), K22 = uniform_f(Kb[8]);
    const bool spec = (K01 == 0.f) && (K10 == 0.f) && (K20 == 0.f) &&
                      (K21 == 0.f) && (K22 == 1.f);
    const float cxfx = K02 * fast_rcp(K00);
    const float cyfy = K12 * fast_rcp(K11);

    // ---- this half's point data, pairwise packed, in registers ----
    v2f X2[NP], Y2[NP], Z2[NP], Au2[NP], Av2[NP], Bu2[NP], Bv2[NP];
    if (EXACT) {
        // N == 256*NP; half wh owns contiguous points [wh*128*NP, ...+128*NP);
        // lane owns 2*NP contiguous points within the half.
        const float4* p3 = reinterpret_cast<const float4*>(x3d + (size_t)item * N * 3)
                           + wh * (3 * NP * 32) + lane * (6 * NP / 4);
        const float4* p2 = reinterpret_cast<const float4*>(x2d + (size_t)item * N * 2)
                           + wh * (2 * NP * 32) + lane * NP;
        const float4* pw = reinterpret_cast<const float4*>(w2d + (size_t)item * N * 2)
                           + wh * (2 * NP * 32) + lane * NP;
        float f3[6 * NP];
#pragma unroll
        for (int i = 0; i < 6 * NP / 4; ++i) {
            const float4 t = p3[i];
            f3[4 * i] = t.x; f3[4 * i + 1] = t.y; f3[4 * i + 2] = t.z; f3[4 * i + 3] = t.w;
        }
#pragma unroll
        for (int j = 0; j < NP; ++j) {
            X2[j].x = f3[6 * j];     X2[j].y = f3[6 * j + 3];
            Y2[j].x = f3[6 * j + 1]; Y2[j].y = f3[6 * j + 4];
            Z2[j].x = f3[6 * j + 2]; Z2[j].y = f3[6 * j + 5];
        }
#pragma unroll
        for (int j = 0; j < NP; ++j) {
            const float4 tw = pw[j];   // (wu0,wv0,wu1,wv1) of pair j
            const float4 to = p2[j];   // (u0,v0,u1,v1)
            if (spec) {
                Au2[j].x = tw.x * K00;          Au2[j].y = tw.z * K00;
                Av2[j].x = tw.y * K11;          Av2[j].y = tw.w * K11;
                Bu2[j].x = tw.x * (K02 - to.x); Bu2[j].y = tw.z * (K02 - to.z);
                Bv2[j].x = tw.y * (K12 - to.y); Bv2[j].y = tw.w * (K12 - to.w);
            } else {
                Au2[j].x = tw.x;         Au2[j].y = tw.z;
                Av2[j].x = tw.y;         Av2[j].y = tw.w;
                Bu2[j].x = -tw.x * to.x; Bu2[j].y = -tw.z * to.z;
                Bv2[j].x = -tw.y * to.y; Bv2[j].y = -tw.w * to.w;
            }
        }
    } else {
        const float* x3b = x3d + (size_t)item * N * 3;
        const float* x2b = x2d + (size_t)item * N * 2;
        const float* w2b = w2d + (size_t)item * N * 2;
#pragma unroll
        for (int j = 0; j < NP; ++j) {
#pragma unroll
            for (int h = 0; h < 2; ++h) {
                const int p = wh * (NP * 128) + (2 * j + h) * 64 + lane;
                float X = 0.f, Y = 0.f, Z = 0.f, au = 0.f, av = 0.f, bu = 0.f, bv = 0.f;
                if (p < N) {
                    X = x3b[3 * p]; Y = x3b[3 * p + 1]; Z = x3b[3 * p + 2];
                    const float wu = w2b[2 * p], wv = w2b[2 * p + 1];
                    const float uo = x2b[2 * p], vo = x2b[2 * p + 1];
                    if (spec) {
                        au = wu * K00;        av = wv * K11;
                        bu = wu * (K02 - uo); bv = wv * (K12 - vo);
                    } else {
                        au = wu;       av = wv;
                        bu = -wu * uo; bv = -wv * vo;
                    }
                }
                if (h == 0) { X2[j].x = X; Y2[j].x = Y; Z2[j].x = Z;
                              Au2[j].x = au; Av2[j].x = av; Bu2[j].x = bu; Bv2[j].x = bv; }
                else        { X2[j].y = X; Y2[j].y = Y; Z2[j].y = Z;
                              Au2[j].y = au; Av2[j].y = av; Bu2[j].y = bu; Bv2[j].y = bv; }
            }
        }
    }

    // ---- wave-uniform control state (identical on both halves) ----
    float JtJ[10], grad[4];
    float cost = 0.f, radius = 30.0f, dec = 2.0f, mcc = 0.f;
#pragma unroll
    for (int k = 0; k < 10; ++k) JtJ[k] = 0.f;
#pragma unroll
    for (int k = 0; k < 4; ++k) grad[k] = 0.f;

    float ax = pose_init[(size_t)item * 4 + 0];
    float ay = pose_init[(size_t)item * 4 + 1];
    float az = pose_init[(size_t)item * 4 + 2];
    float ayaw = pose_init[(size_t)item * 4 + 3];
    float ex = ax, ey = ay, ez = az, eyaw = ayaw;
    float sn = __sinf(eyaw), cs = __cosf(eyaw);

#pragma clang loop unroll(disable)
    for (int it = 0; it <= NUM_ITER; ++it) {
        // acc: 0..9 JtJ upper-tri (00,01,02,03,11,12,13,22,23,33),
        //      10..13 grad, 14 = sum r^2
        float acc[15];
        const int par = it & 1;

        // Exactly ONE __syncthreads per iteration in both paths.
        if (spec) {
            // map: 0:00 1:02 2:03 3:11 4:12 5:13 6:22 7:23 8:33 9..12:grad 13:r^2
            v2f s2[14];
#pragma unroll
            for (int k = 0; k < 14; ++k) s2[k] = (v2f)(0.f);
            const v2f cs2 = (v2f)(cs),  sn2 = (v2f)(sn);
            const v2f ex2 = (v2f)(ex),  ey2 = (v2f)(ey), ez2 = (v2f)(ez);
            const v2f zm2 = (v2f)(Z_MIN);
#pragma unroll
            for (int j = 0; j < NP; ++j) {
                const v2f X = X2[j], Y = Y2[j], Z = Z2[j];
                const v2f px = fma2(cs2, X, fma2(sn2, Z, ex2));
                const v2f py = Y + ey2;
                const v2f pz = fma2(-sn2, X, fma2(cs2, Z, ez2));
                const v2f zc = max2(pz, zm2);
                v2f inv; inv.x = fast_rcp(zc.x); inv.y = fast_rcp(zc.y);
                const v2f alpha = px * inv;
                const v2f beta  = py * inv;
                v2f t, tv;
                t.x  = (pz.x > Z_MIN) ? -alpha.x : cxfx;
                t.y  = (pz.y > Z_MIN) ? -alpha.y : cxfx;
                tv.x = (pz.x > Z_MIN) ? -beta.x  : cyfy;
                tv.y = (pz.y > Z_MIN) ? -beta.y  : cyfy;
                const v2f ru  = fma2(Au2[j], alpha, Bu2[j]);
                const v2f rv  = fma2(Av2[j], beta,  Bv2[j]);
                const v2f Ju0 = Au2[j] * inv;
                const v2f Jv1 = Av2[j] * inv;
                const v2f Ju2 = Ju0 * t;
                const v2f Jv2 = Jv1 * tv;
                const v2f a  = pz - ez2;
                const v2f bb = ex2 - px;
                const v2f q  = fma2(t, bb, a);
                const v2f Ju3 = Ju0 * q;
                const v2f Jv3 = Jv2 * bb;
                s2[0]  = fma2(Ju0, Ju0, s2[0]);
                s2[1]  = fma2(Ju0, Ju2, s2[1]);
                s2[2]  = fma2(Ju0, Ju3, s2[2]);
                s2[3]  = fma2(Jv1, Jv1, s2[3]);
                s2[4]  = fma2(Jv1, Jv2, s2[4]);
                s2[5]  = fma2(Jv1, Jv3, s2[5]);
                s2[6]  = fma2(Ju2, Ju2, fma2(Jv2, Jv2, s2[6]));
                s2[7]  = fma2(Ju2, Ju3, fma2(Jv2, Jv3, s2[7]));
                s2[8]  = fma2(Ju3, Ju3, fma2(Jv3, Jv3, s2[8]));
                s2[9]  = fma2(Ju0, ru, s2[9]);
                s2[10] = fma2(Jv1, rv, s2[10]);
                s2[11] = fma2(Ju2, ru, fma2(Jv2, rv, s2[11]));
                s2[12] = fma2(Ju3, ru, fma2(Jv3, rv, s2[12]));
                s2[13] = fma2(ru, ru, fma2(rv, rv, s2[13]));
            }
            float s[14];
#pragma unroll
            for (int k = 0; k < 14; ++k) s[k] = s2[k].x + s2[k].y;
            wave_reduce_uniform<14>(s);
            // cross-half combine via LDS (double-buffered on parity)
            if (lane == 0) {
#pragma unroll
                for (int k = 0; k < 14; ++k) red[ib][par][wh][k] = s[k];
            }
            __syncthreads();
#pragma unroll
            for (int k = 0; k < 14; ++k) s[k] += red[ib][par][wh ^ 1][k];
            acc[0] = s[0];  acc[1] = 0.f;  acc[2] = s[1];  acc[3] = s[2];
            acc[4] = s[3];  acc[5] = s[4]; acc[6] = s[5];  acc[7] = s[6];
            acc[8] = s[7];  acc[9] = s[8];
            acc[10] = s[9]; acc[11] = s[10]; acc[12] = s[11]; acc[13] = s[12];
            acc[14] = s[13];
        } else {
#pragma unroll
            for (int k = 0; k < 15; ++k) acc[k] = 0.f;
#pragma unroll
            for (int j = 0; j < NP; ++j) {
#pragma unroll
                for (int h = 0; h < 2; ++h) {
                    const float X = h ? X2[j].y : X2[j].x;
                    const float Y = h ? Y2[j].y : Y2[j].x;
                    const float Z = h ? Z2[j].y : Z2[j].x;
                    const float au = h ? Au2[j].y : Au2[j].x;
                    const float av = h ? Av2[j].y : Av2[j].x;
                    const float bu = h ? Bu2[j].y : Bu2[j].x;
                    const float bv = h ? Bv2[j].y : Bv2[j].x;
                    const float px = fmaf(cs, X, fmaf(sn, Z, ex));
                    const float py = Y + ey;
                    const float pz = fmaf(-sn, X, fmaf(cs, Z, ez));
                    const float nu = fmaf(K00, px, fmaf(K01, py, K02 * pz));
                    const float nv = fmaf(K10, px, fmaf(K11, py, K12 * pz));
                    const float w  = fmaf(K20, px, fmaf(K21, py, K22 * pz));
                    const float zc  = fmaxf(w, Z_MIN);
                    const float inv = fast_rcp(zc);
                    const float gu = au * inv, gv = av * inv;
                    const float ru = fmaf(nu, gu, bu);
                    const float rv = fmaf(nv, gv, bv);
                    const float u = nu * inv, v = nv * inv;
                    const float fl  = (w > Z_MIN) ? 1.f : 0.f;
                    const float ufl = u * fl, vfl = v * fl;
                    const float a  = pz - ez;
                    const float bb = ex - px;
                    const float dnu3 = fmaf(K00, a, K02 * bb);
                    const float dnv3 = fmaf(K10, a, K12 * bb);
                    const float dw3  = fmaf(K20, a, K22 * bb);
                    float Ju[4], Jv[4];
                    Ju[0] = gu * fmaf(-ufl, K20, K00);  Jv[0] = gv * fmaf(-vfl, K20, K10);
                    Ju[1] = gu * fmaf(-ufl, K21, K01);  Jv[1] = gv * fmaf(-vfl, K21, K11);
                    Ju[2] = gu * fmaf(-ufl, K22, K02);  Jv[2] = gv * fmaf(-vfl, K22, K12);
                    Ju[3] = gu * fmaf(-ufl, dw3, dnu3); Jv[3] = gv * fmaf(-vfl, dw3, dnv3);
                    int idx = 0;
#pragma unroll
                    for (int r = 0; r < 4; ++r)
#pragma unroll
                        for (int c = r; c < 4; ++c) {
                            acc[idx] = fmaf(Ju[r], Ju[c], fmaf(Jv[r], Jv[c], acc[idx]));
                            ++idx;
                        }
#pragma unroll
                    for (int r = 0; r < 4; ++r)
                        acc[10 + r] = fmaf(Ju[r], ru, fmaf(Jv[r], rv, acc[10 + r]));
                    acc[14] = fmaf(ru, ru, fmaf(rv, rv, acc[14]));
                }
            }
            wave_reduce_uniform<15>(acc);
            if (lane == 0) {
#pragma unroll
                for (int k = 0; k < 15; ++k) red[ib][par][wh][k] = acc[k];
            }
            __syncthreads();
#pragma unroll
            for (int k = 0; k < 15; ++k) acc[k] += red[ib][par][wh ^ 1][k];
        }

        const float costN = 0.5f * acc[14];

        // ---- accept / reject (identical on both halves, f32) ----
        bool accept;
        if (it == 0) {
            accept = true;
        } else {
            const float rel = (cost - costN) * fast_rcp(mcc);
            const bool success = (rel >= 1e-3f) && (mcc > 0.0f);
            if (success) {
                const float q = 2.0f * rel - 1.0f;
                const float denom = fmaxf(1.0f - q * q * q, 1.0f / 3.0f);
                radius = fminf(radius * fast_rcp(denom), 1e16f);
                dec = 2.0f;
            } else {
                radius = radius * fast_rcp(dec);
                dec = dec * 2.0f;
            }
            accept = success;
        }
        if (accept) {
#pragma unroll
            for (int k = 0; k < 10; ++k) JtJ[k] = acc[k];
#pragma unroll
            for (int k = 0; k < 4; ++k) grad[k] = acc[10 + k];
            cost = costN;
            if (it > 0) { ax = ex; ay = ey; az = ez; ayaw = eyaw; }
        }

        if (it < NUM_ITER) {
            float A[10], rhs[4], stf[4];
#pragma unroll
            for (int k = 0; k < 10; ++k) A[k] = JtJ[k];
            const float irad = fast_rcp(radius);
            const float e0 = fminf(fmaxf(JtJ[0], 1e-6f), 1e32f) * irad;
            const float e1 = fminf(fmaxf(JtJ[4], 1e-6f), 1e32f) * irad;
            const float e2 = fminf(fmaxf(JtJ[7], 1e-6f), 1e32f) * irad;
            const float e3 = fminf(fmaxf(JtJ[9], 1e-6f), 1e32f) * irad;
            A[0] += e0; A[4] += e1; A[7] += e2; A[9] += e3;
#pragma unroll
            for (int r = 0; r < 4; ++r) rhs[r] = -grad[r];
            solve4_spd(A, rhs, stf);
            ex = ax + stf[0]; ey = ay + stf[1]; ez = az + stf[2]; eyaw = ayaw + stf[3];
            // mcc via damping identity: s'JtJ s = -s'g - sum(e_i s_i^2)
            const float s0 = stf[0], s1 = stf[1], s2 = stf[2], s3 = stf[3];
            const float sg = s0 * grad[0] + s1 * grad[1] + s2 * grad[2] + s3 * grad[3];
            float sd = e0 * s0 * s0;
            sd = fmaf(e1 * s1, s1, sd);
            sd = fmaf(e2 * s2, s2, sd);
            sd = fmaf(e3 * s3, s3, sd);
            mcc = 0.5f * (sd - sg);
            sn = __sinf(eyaw); cs = __cosf(eyaw);
        } else if (valid && wh == 0 && lane == 0) {
            // epilogue: pose_opt, cost, pose_opt + GN step (half 0 writes)
            float* out_pose = out;
            float* out_cost = out + (size_t)B * 4;
            float* out_plus = out + (size_t)B * 5;
            out_pose[(size_t)item * 4 + 0] = ax;
            out_pose[(size_t)item * 4 + 1] = ay;
            out_pose[(size_t)item * 4 + 2] = az;
            out_pose[(size_t)item * 4 + 3] = ayaw;
            out_cost[item] = cost;
            float A[10], rhs[4], stf[4];
#pragma unroll
            for (int k = 0; k < 10; ++k) A[k] = JtJ[k];
            A[0] += 1e-5f; A[4] += 1e-5f; A[7] += 1e-5f; A[9] += 1e-5f;
#pragma unroll
            for (int r = 0; r < 4; ++r) rhs[r] = -grad[r];
            solve4_spd(A, rhs, stf);
            out_plus[(size_t)item * 4 + 0] = ax + stf[0];
            out_plus[(size_t)item * 4 + 1] = ay + stf[1];
            out_plus[(size_t)item * 4 + 2] = az + stf[2];
            out_plus[(size_t)item * 4 + 3] = ayaw + stf[3];
        }
    }
}

extern "C" void kernel_launch(void* const* d_in, const int* in_sizes, int n_in,
                              void* d_out, int out_size, void* d_ws, size_t ws_size,
                              hipStream_t stream) {
    const float* x3d       = (const float*)d_in[0];
    const float* x2d       = (const float*)d_in[1];
    const float* w2d       = (const float*)d_in[2];
    const float* pose_init = (const float*)d_in[3];
    const float* cam       = (const float*)d_in[4];
    float* out = (float*)d_out;

    const int B = in_sizes[3] / 4;
    const int N = in_sizes[0] / (3 * B);
    const int grid = (B + 1) / 2;   // 2 items per block

    if (N == 512) {
        lm_kernel2<2, true><<<grid, 256, 0, stream>>>(x3d, x2d, w2d, pose_init, cam, out, B, N);
    } else if (N <= 256) {
        lm_kernel2<1, false><<<grid, 256, 0, stream>>>(x3d, x2d, w2d, pose_init, cam, out, B, N);
    } else if (N <= 512) {
        lm_kernel2<2, false><<<grid, 256, 0, stream>>>(x3d, x2d, w2d, pose_init, cam, out, B, N);
    } else if (N <= 1024) {
        lm_kernel2<4, false><<<grid, 256, 0, stream>>>(x3d, x2d, w2d, pose_init, cam, out, B, N);
    } else {
        lm_kernel2<8, false><<<grid, 256, 0, stream>>>(x3d, x2d, w2d, pose_init, cam, out, B, N);
    }
}

// Round 14
// 125.779 us; speedup vs baseline: 1.1348x; 1.1348x over previous
//
#include <hip/hip_runtime.h>
#include <math.h>

#define NUM_ITER 10
#define Z_MIN 0.1f

typedef float v2f __attribute__((ext_vector_type(2)));

__device__ inline float uniform_f(float v) {
    // item is wave-uniform -> force value into an SGPR
    return __int_as_float(__builtin_amdgcn_readfirstlane(__float_as_int(v)));
}

__device__ inline float fast_rcp(float x) {
    return __builtin_amdgcn_rcpf(x);
}

__device__ inline v2f fma2(v2f a, v2f b, v2f c) {
#if __has_builtin(__builtin_elementwise_fma)
    return __builtin_elementwise_fma(a, b, c);   // -> v_pk_fma_f32
#else
    v2f r; r.x = fmaf(a.x, b.x, c.x); r.y = fmaf(a.y, b.y, c.y); return r;
#endif
}

__device__ inline v2f max2(v2f a, v2f b) {
#if __has_builtin(__builtin_elementwise_max)
    return __builtin_elementwise_max(a, b);
#else
    v2f r; r.x = fmaxf(a.x, b.x); r.y = fmaxf(a.y, b.y); return r;
#endif
}

// Full-wave (64-lane) reduce, ALL-VALU (no DS pipe, no lgkm waits):
// 4x DPP row_ror + row_bcast15 + row_bcast31 -> total in lanes 48-63;
// v_readlane lane 63 -> SGPR, uniform across the wave. Stage-major for ILP.
template <int M>
__device__ inline void wave_reduce_uniform(float (&a)[M]) {
#pragma unroll
    for (int k = 0; k < M; ++k) {
        int t = __builtin_amdgcn_update_dpp(0, __float_as_int(a[k]), 0x121, 0xf, 0xf, true);
        a[k] += __int_as_float(t);  // ror:1
    }
#pragma unroll
    for (int k = 0; k < M; ++k) {
        int t = __builtin_amdgcn_update_dpp(0, __float_as_int(a[k]), 0x122, 0xf, 0xf, true);
        a[k] += __int_as_float(t);  // ror:2
    }
#pragma unroll
    for (int k = 0; k < M; ++k) {
        int t = __builtin_amdgcn_update_dpp(0, __float_as_int(a[k]), 0x124, 0xf, 0xf, true);
        a[k] += __int_as_float(t);  // ror:4
    }
#pragma unroll
    for (int k = 0; k < M; ++k) {
        int t = __builtin_amdgcn_update_dpp(0, __float_as_int(a[k]), 0x128, 0xf, 0xf, true);
        a[k] += __int_as_float(t);  // ror:8
    }
#pragma unroll
    for (int k = 0; k < M; ++k) {
        int t = __builtin_amdgcn_update_dpp(0, __float_as_int(a[k]), 0x142, 0xf, 0xf, true);
        a[k] += __int_as_float(t);  // row_bcast15
    }
#pragma unroll
    for (int k = 0; k < M; ++k) {
        int t = __builtin_amdgcn_update_dpp(0, __float_as_int(a[k]), 0x143, 0xf, 0xf, true);
        a[k] += __int_as_float(t);  // row_bcast31
    }
#pragma unroll
    for (int k = 0; k < M; ++k) {
        a[k] = __int_as_float(__builtin_amdgcn_readlane(__float_as_int(a[k]), 63));
    }
}

// Branchless f32 LDL^T solve of 4x4 SPD system. t = upper-tri packed
// (00,01,02,03,11,12,13,22,23,33), solves A x = b.  Uses fast rcp.
__device__ inline void solve4_spd(const float t[10], const float b[4], float x[4]) {
    const float d0 = t[0];
    const float i0 = fast_rcp(d0);
    const float L10 = t[1] * i0, L20 = t[2] * i0, L30 = t[3] * i0;
    const float d1 = t[4] - L10 * t[1];
    const float i1 = fast_rcp(d1);
    const float L21 = (t[5] - L20 * t[1]) * i1;
    const float L31 = (t[6] - L30 * t[1]) * i1;
    const float d2 = t[7] - L20 * t[2] - L21 * L21 * d1;
    const float i2 = fast_rcp(d2);
    const float L32 = (t[8] - L30 * t[2] - L31 * L21 * d1) * i2;
    const float d3 = t[9] - L30 * t[3] - L31 * L31 * d1 - L32 * L32 * d2;
    const float i3 = fast_rcp(d3);
    const float y0 = b[0];
    const float y1 = b[1] - L10 * y0;
    const float y2 = b[2] - L20 * y0 - L21 * y1;
    const float y3 = b[3] - L30 * y0 - L31 * y1 - L32 * y2;
    const float z0 = y0 * i0, z1 = y1 * i1, z2 = y2 * i2, z3 = y3 * i3;
    x[3] = z3;
    x[2] = z2 - L32 * z3;
    x[1] = z1 - L21 * x[2] - L31 * x[3];
    x[0] = z0 - L10 * x[1] - L20 * x[2] - L30 * x[3];
}

// FINAL (R10 structure, verified best: dispatch ~49 us, bench ~126 us).
// One wave (64 lanes) per batch item; 4 independent waves per 256-block.
// Points held in VGPRs, processed in PAIRS with packed-f32 (v_pk_*) math.
// - NO min-waves launch-bounds arg: a register cap makes the allocator
//   dump the point arrays to scratch wholesale (R2-R3: 0.9 GB traffic).
// - No LDS, no __syncthreads, no DS-pipe ops (R9: +20% vs ds_swizzle).
// - Rolled iteration loop (R10, neutral but compact).
// Falsified alternatives: i-cache rolling (R10), wave de-phasing (R11),
// 2-wave-per-item split for occupancy (R13: barrier+duplication > gain).
template <int PPL, bool EXACT>
__global__ __launch_bounds__(256) void lm_kernel(
    const float* __restrict__ x3d, const float* __restrict__ x2d,
    const float* __restrict__ w2d, const float* __restrict__ pose_init,
    const float* __restrict__ K, float* __restrict__ out, int B, int N)
{
    static_assert(PPL % 2 == 0, "PPL must be even");
    constexpr int NP = PPL / 2;  // pairs per lane

    const int wave = threadIdx.x >> 6;
    const int lane = threadIdx.x & 63;
    const int item = blockIdx.x * 4 + wave;
    if (item >= B) return;  // wave-uniform

    // ---- K: loop-invariant, wave-uniform -> SGPRs ----
    const float* Kb = K + (size_t)item * 9;
    const float K00 = uniform_f(Kb[0]), K01 = uniform_f(Kb[1]), K02 = uniform_f(Kb[2]);
    const float K10 = uniform_f(Kb[3]), K11 = uniform_f(Kb[4]), K12 = uniform_f(Kb[5]);
    const float K20 = uniform_f(Kb[6]), K21 = uniform_f(Kb[7]), K22 = uniform_f(Kb[8]);
    const bool spec = (K01 == 0.f) && (K10 == 0.f) && (K20 == 0.f) &&
                      (K21 == 0.f) && (K22 == 1.f);
    const float cxfx = K02 * fast_rcp(K00);  // out-of-range Ju2 factor
    const float cyfy = K12 * fast_rcp(K11);

    // ---- point data in registers, pairwise packed (read exactly once) ----
    v2f X2[NP], Y2[NP], Z2[NP], Au2[NP], Av2[NP], Bu2[NP], Bv2[NP];
    if (EXACT) {
        const float4* p3 = reinterpret_cast<const float4*>(x3d + (size_t)item * N * 3) + lane * (3 * PPL / 4);
        const float4* p2 = reinterpret_cast<const float4*>(x2d + (size_t)item * N * 2) + lane * (2 * PPL / 4);
        const float4* pw = reinterpret_cast<const float4*>(w2d + (size_t)item * N * 2) + lane * (2 * PPL / 4);
        float f3[3 * PPL];
#pragma unroll
        for (int i = 0; i < 3 * PPL / 4; ++i) {
            const float4 t = p3[i];
            f3[4 * i] = t.x; f3[4 * i + 1] = t.y; f3[4 * i + 2] = t.z; f3[4 * i + 3] = t.w;
        }
#pragma unroll
        for (int j = 0; j < NP; ++j) {
            X2[j].x = f3[6 * j];     X2[j].y = f3[6 * j + 3];
            Y2[j].x = f3[6 * j + 1]; Y2[j].y = f3[6 * j + 4];
            Z2[j].x = f3[6 * j + 2]; Z2[j].y = f3[6 * j + 5];
        }
#pragma unroll
        for (int j = 0; j < NP; ++j) {
            const float4 tw = pw[j];
            const float4 to = p2[j];
            if (spec) {
                Au2[j].x = tw.x * K00;          Au2[j].y = tw.z * K00;
                Av2[j].x = tw.y * K11;          Av2[j].y = tw.w * K11;
                Bu2[j].x = tw.x * (K02 - to.x); Bu2[j].y = tw.z * (K02 - to.z);
                Bv2[j].x = tw.y * (K12 - to.y); Bv2[j].y = tw.w * (K12 - to.w);
            } else {
                Au2[j].x = tw.x;         Au2[j].y = tw.z;
                Av2[j].x = tw.y;         Av2[j].y = tw.w;
                Bu2[j].x = -tw.x * to.x; Bu2[j].y = -tw.z * to.z;
                Bv2[j].x = -tw.y * to.y; Bv2[j].y = -tw.w * to.w;
            }
        }
    } else {
        const float* x3b = x3d + (size_t)item * N * 3;
        const float* x2b = x2d + (size_t)item * N * 2;
        const float* w2b = w2d + (size_t)item * N * 2;
#pragma unroll
        for (int j = 0; j < NP; ++j) {
#pragma unroll
            for (int h = 0; h < 2; ++h) {
                const int p = lane + (2 * j + h) * 64;
                float X = 0.f, Y = 0.f, Z = 0.f, au = 0.f, av = 0.f, bu = 0.f, bv = 0.f;
                if (p < N) {
                    X = x3b[3 * p]; Y = x3b[3 * p + 1]; Z = x3b[3 * p + 2];
                    const float wu = w2b[2 * p], wv = w2b[2 * p + 1];
                    const float uo = x2b[2 * p], vo = x2b[2 * p + 1];
                    if (spec) {
                        au = wu * K00;        av = wv * K11;
                        bu = wu * (K02 - uo); bv = wv * (K12 - vo);
                    } else {
                        au = wu;       av = wv;
                        bu = -wu * uo; bv = -wv * vo;
                    }
                }
                if (h == 0) { X2[j].x = X; Y2[j].x = Y; Z2[j].x = Z;
                              Au2[j].x = au; Av2[j].x = av; Bu2[j].x = bu; Bv2[j].x = bv; }
                else        { X2[j].y = X; Y2[j].y = Y; Z2[j].y = Z;
                              Au2[j].y = au; Av2[j].y = av; Bu2[j].y = bu; Bv2[j].y = bv; }
            }
        }
    }

    // ---- wave-uniform control state (redundant on all 64 lanes, f32) ----
    float JtJ[10], grad[4];
    float cost = 0.f, radius = 30.0f, dec = 2.0f, mcc = 0.f;
#pragma unroll
    for (int k = 0; k < 10; ++k) JtJ[k] = 0.f;
#pragma unroll
    for (int k = 0; k < 4; ++k) grad[k] = 0.f;

    float ax = pose_init[(size_t)item * 4 + 0];
    float ay = pose_init[(size_t)item * 4 + 1];
    float az = pose_init[(size_t)item * 4 + 2];
    float ayaw = pose_init[(size_t)item * 4 + 3];
    float ex = ax, ey = ay, ez = az, eyaw = ayaw;
    float sn = __sinf(eyaw), cs = __cosf(eyaw);

#pragma clang loop unroll(disable)
    for (int it = 0; it <= NUM_ITER; ++it) {
        // acc: 0..9 JtJ upper-tri (00,01,02,03,11,12,13,22,23,33),
        //      10..13 grad, 14 = sum r^2
        float acc[15];

        if (spec) {
            // map: 0:00 1:02 2:03 3:11 4:12 5:13 6:22 7:23 8:33 9..12:grad 13:r^2
            v2f s2[14];
#pragma unroll
            for (int k = 0; k < 14; ++k) s2[k] = (v2f)(0.f);
            const v2f cs2 = (v2f)(cs),  sn2 = (v2f)(sn);
            const v2f ex2 = (v2f)(ex),  ey2 = (v2f)(ey), ez2 = (v2f)(ez);
            const v2f zm2 = (v2f)(Z_MIN);
#pragma unroll
            for (int j = 0; j < NP; ++j) {
                const v2f X = X2[j], Y = Y2[j], Z = Z2[j];
                const v2f px = fma2(cs2, X, fma2(sn2, Z, ex2));
                const v2f py = Y + ey2;
                const v2f pz = fma2(-sn2, X, fma2(cs2, Z, ez2));
                const v2f zc = max2(pz, zm2);
                v2f inv; inv.x = fast_rcp(zc.x); inv.y = fast_rcp(zc.y);
                const v2f alpha = px * inv;
                const v2f beta  = py * inv;
                v2f t, tv;
                t.x  = (pz.x > Z_MIN) ? -alpha.x : cxfx;
                t.y  = (pz.y > Z_MIN) ? -alpha.y : cxfx;
                tv.x = (pz.x > Z_MIN) ? -beta.x  : cyfy;
                tv.y = (pz.y > Z_MIN) ? -beta.y  : cyfy;
                const v2f ru  = fma2(Au2[j], alpha, Bu2[j]);
                const v2f rv  = fma2(Av2[j], beta,  Bv2[j]);
                const v2f Ju0 = Au2[j] * inv;
                const v2f Jv1 = Av2[j] * inv;
                const v2f Ju2 = Ju0 * t;
                const v2f Jv2 = Jv1 * tv;
                const v2f a  = pz - ez2;   // -s*X + c*Z
                const v2f bb = ex2 - px;   // -(c*X + s*Z)
                const v2f q  = fma2(t, bb, a);
                const v2f Ju3 = Ju0 * q;
                const v2f Jv3 = Jv2 * bb;
                s2[0]  = fma2(Ju0, Ju0, s2[0]);
                s2[1]  = fma2(Ju0, Ju2, s2[1]);
                s2[2]  = fma2(Ju0, Ju3, s2[2]);
                s2[3]  = fma2(Jv1, Jv1, s2[3]);
                s2[4]  = fma2(Jv1, Jv2, s2[4]);
                s2[5]  = fma2(Jv1, Jv3, s2[5]);
                s2[6]  = fma2(Ju2, Ju2, fma2(Jv2, Jv2, s2[6]));
                s2[7]  = fma2(Ju2, Ju3, fma2(Jv2, Jv3, s2[7]));
                s2[8]  = fma2(Ju3, Ju3, fma2(Jv3, Jv3, s2[8]));
                s2[9]  = fma2(Ju0, ru, s2[9]);
                s2[10] = fma2(Jv1, rv, s2[10]);
                s2[11] = fma2(Ju2, ru, fma2(Jv2, rv, s2[11]));
                s2[12] = fma2(Ju3, ru, fma2(Jv3, rv, s2[12]));
                s2[13] = fma2(ru, ru, fma2(rv, rv, s2[13]));
            }
            float s[14];
#pragma unroll
            for (int k = 0; k < 14; ++k) s[k] = s2[k].x + s2[k].y;
            wave_reduce_uniform<14>(s);
            acc[0] = s[0];  acc[1] = 0.f;  acc[2] = s[1];  acc[3] = s[2];
            acc[4] = s[3];  acc[5] = s[4]; acc[6] = s[5];  acc[7] = s[6];
            acc[8] = s[7];  acc[9] = s[8];
            acc[10] = s[9]; acc[11] = s[10]; acc[12] = s[11]; acc[13] = s[12];
            acc[14] = s[13];
        } else {
#pragma unroll
            for (int k = 0; k < 15; ++k) acc[k] = 0.f;
#pragma unroll
            for (int j = 0; j < NP; ++j) {
#pragma unroll
                for (int h = 0; h < 2; ++h) {
                    const float X = h ? X2[j].y : X2[j].x;
                    const float Y = h ? Y2[j].y : Y2[j].x;
                    const float Z = h ? Z2[j].y : Z2[j].x;
                    const float au = h ? Au2[j].y : Au2[j].x;
                    const float av = h ? Av2[j].y : Av2[j].x;
                    const float bu = h ? Bu2[j].y : Bu2[j].x;
                    const float bv = h ? Bv2[j].y : Bv2[j].x;
                    const float px = fmaf(cs, X, fmaf(sn, Z, ex));
                    const float py = Y + ey;
                    const float pz = fmaf(-sn, X, fmaf(cs, Z, ez));
                    const float nu = fmaf(K00, px, fmaf(K01, py, K02 * pz));
                    const float nv = fmaf(K10, px, fmaf(K11, py, K12 * pz));
                    const float w  = fmaf(K20, px, fmaf(K21, py, K22 * pz));
                    const float zc  = fmaxf(w, Z_MIN);
                    const float inv = fast_rcp(zc);
                    const float gu = au * inv, gv = av * inv;
                    const float ru = fmaf(nu, gu, bu);
                    const float rv = fmaf(nv, gv, bv);
                    const float u = nu * inv, v = nv * inv;
                    const float fl  = (w > Z_MIN) ? 1.f : 0.f;
                    const float ufl = u * fl, vfl = v * fl;
                    const float a  = pz - ez;
                    const float bb = ex - px;
                    const float dnu3 = fmaf(K00, a, K02 * bb);
                    const float dnv3 = fmaf(K10, a, K12 * bb);
                    const float dw3  = fmaf(K20, a, K22 * bb);
                    float Ju[4], Jv[4];
                    Ju[0] = gu * fmaf(-ufl, K20, K00);  Jv[0] = gv * fmaf(-vfl, K20, K10);
                    Ju[1] = gu * fmaf(-ufl, K21, K01);  Jv[1] = gv * fmaf(-vfl, K21, K11);
                    Ju[2] = gu * fmaf(-ufl, K22, K02);  Jv[2] = gv * fmaf(-vfl, K22, K12);
                    Ju[3] = gu * fmaf(-ufl, dw3, dnu3); Jv[3] = gv * fmaf(-vfl, dw3, dnv3);
                    int idx = 0;
#pragma unroll
                    for (int r = 0; r < 4; ++r)
#pragma unroll
                        for (int c = r; c < 4; ++c) {
                            acc[idx] = fmaf(Ju[r], Ju[c], fmaf(Jv[r], Jv[c], acc[idx]));
                            ++idx;
                        }
#pragma unroll
                    for (int r = 0; r < 4; ++r)
                        acc[10 + r] = fmaf(Ju[r], ru, fmaf(Jv[r], rv, acc[10 + r]));
                    acc[14] = fmaf(ru, ru, fmaf(rv, rv, acc[14]));
                }
            }
            wave_reduce_uniform<15>(acc);
        }

        const float costN = 0.5f * acc[14];

        // ---- accept / reject (wave-uniform, f32 like reference) ----
        bool accept;
        if (it == 0) {
            accept = true;
        } else {
            const float rel = (cost - costN) * fast_rcp(mcc);
            const bool success = (rel >= 1e-3f) && (mcc > 0.0f);
            if (success) {
                const float q = 2.0f * rel - 1.0f;
                const float denom = fmaxf(1.0f - q * q * q, 1.0f / 3.0f);
                radius = fminf(radius * fast_rcp(denom), 1e16f);
                dec = 2.0f;
            } else {
                radius = radius * fast_rcp(dec);  // dec = 2^k, rcp exact
                dec = dec * 2.0f;
            }
            accept = success;
        }
        if (accept) {
#pragma unroll
            for (int k = 0; k < 10; ++k) JtJ[k] = acc[k];
#pragma unroll
            for (int k = 0; k < 4; ++k) grad[k] = acc[10 + k];
            cost = costN;
            if (it > 0) { ax = ex; ay = ey; az = ez; ayaw = eyaw; }
        }

        if (it < NUM_ITER) {
            // LM-damped solve from accepted state
            float A[10], rhs[4], stf[4];
#pragma unroll
            for (int k = 0; k < 10; ++k) A[k] = JtJ[k];
            const float irad = fast_rcp(radius);
            const float e0 = fminf(fmaxf(JtJ[0], 1e-6f), 1e32f) * irad;
            const float e1 = fminf(fmaxf(JtJ[4], 1e-6f), 1e32f) * irad;
            const float e2 = fminf(fmaxf(JtJ[7], 1e-6f), 1e32f) * irad;
            const float e3 = fminf(fmaxf(JtJ[9], 1e-6f), 1e32f) * irad;
            A[0] += e0; A[4] += e1; A[7] += e2; A[9] += e3;
#pragma unroll
            for (int r = 0; r < 4; ++r) rhs[r] = -grad[r];
            solve4_spd(A, rhs, stf);
            ex = ax + stf[0]; ey = ay + stf[1]; ez = az + stf[2]; eyaw = ayaw + stf[3];
            // mcc via damping identity: (JtJ+D)s=-g => s'JtJ s = -s'g - sum(e_i s_i^2)
            const float s0 = stf[0], s1 = stf[1], s2 = stf[2], s3 = stf[3];
            const float sg = s0 * grad[0] + s1 * grad[1] + s2 * grad[2] + s3 * grad[3];
            float sd = e0 * s0 * s0;
            sd = fmaf(e1 * s1, s1, sd);
            sd = fmaf(e2 * s2, s2, sd);
            sd = fmaf(e3 * s3, s3, sd);
            mcc = 0.5f * (sd - sg);
            sn = __sinf(eyaw); cs = __cosf(eyaw);
        } else if (lane == 0) {
            // epilogue: pose_opt, cost, pose_opt + GN step
            float* out_pose = out;
            float* out_cost = out + (size_t)B * 4;
            float* out_plus = out + (size_t)B * 5;
            out_pose[(size_t)item * 4 + 0] = ax;
            out_pose[(size_t)item * 4 + 1] = ay;
            out_pose[(size_t)item * 4 + 2] = az;
            out_pose[(size_t)item * 4 + 3] = ayaw;
            out_cost[item] = cost;
            float A[10], rhs[4], stf[4];
#pragma unroll
            for (int k = 0; k < 10; ++k) A[k] = JtJ[k];
            A[0] += 1e-5f; A[4] += 1e-5f; A[7] += 1e-5f; A[9] += 1e-5f;
#pragma unroll
            for (int r = 0; r < 4; ++r) rhs[r] = -grad[r];
            solve4_spd(A, rhs, stf);
            out_plus[(size_t)item * 4 + 0] = ax + stf[0];
            out_plus[(size_t)item * 4 + 1] = ay + stf[1];
            out_plus[(size_t)item * 4 + 2] = az + stf[2];
            out_plus[(size_t)item * 4 + 3] = ayaw + stf[3];
        }
    }
}

extern "C" void kernel_launch(void* const* d_in, const int* in_sizes, int n_in,
                              void* d_out, int out_size, void* d_ws, size_t ws_size,
                              hipStream_t stream) {
    const float* x3d       = (const float*)d_in[0];
    const float* x2d       = (const float*)d_in[1];
    const float* w2d       = (const float*)d_in[2];
    const float* pose_init = (const float*)d_in[3];
    const float* cam       = (const float*)d_in[4];
    float* out = (float*)d_out;

    const int B = in_sizes[3] / 4;
    const int N = in_sizes[0] / (3 * B);
    const int grid = (B + 3) / 4;

    if (N == 512) {
        lm_kernel<8, true><<<grid, 256, 0, stream>>>(x3d, x2d, w2d, pose_init, cam, out, B, N);
    } else if (N == 256) {
        lm_kernel<4, true><<<grid, 256, 0, stream>>>(x3d, x2d, w2d, pose_init, cam, out, B, N);
    } else if (N <= 128) {
        lm_kernel<2, false><<<grid, 256, 0, stream>>>(x3d, x2d, w2d, pose_init, cam, out, B, N);
    } else if (N <= 256) {
        lm_kernel<4, false><<<grid, 256, 0, stream>>>(x3d, x2d, w2d, pose_init, cam, out, B, N);
    } else if (N <= 512) {
        lm_kernel<8, false><<<grid, 256, 0, stream>>>(x3d, x2d, w2d, pose_init, cam, out, B, N);
    } else {
        lm_kernel<16, false><<<grid, 256, 0, stream>>>(x3d, x2d, w2d, pose_init, cam, out, B, N);
    }
}